// Round 11
// baseline (201.592 us; speedup 1.0000x reference)
//
#include <hip/hip_runtime.h>

#define N_ENT   50000
#define N_ENT_P 50176
#define NDIM    256
#define BATCH   1024
#define MROWS   2048
#define AM      64
#define NTILES  196
#define NSTRIP  16
#define SHIFT   30.0f

typedef __attribute__((ext_vector_type(8))) short short8;
typedef __attribute__((ext_vector_type(4))) float f32x4;

__device__ __forceinline__ unsigned short f2bf(float f) {
  unsigned int u = __float_as_uint(f);
  u += 0x7fffu + ((u >> 16) & 1u);          // RNE
  return (unsigned short)(u >> 16);
}

__device__ __forceinline__ void async16(const void* g, void* lds) {
  __builtin_amdgcn_global_load_lds(
      (const __attribute__((address_space(1))) unsigned int*)g,
      (__attribute__((address_space(3))) unsigned int*)lds,
      16, 0, 0);
}

// ---- K0 (fused): blocks [0,3136): ent_w f32 -> bf16 MFMA-FRAGMENT layout
//      (granule (nt,kc,lane)=B[nt*16+ln][kc*32+q*8..+7], 1024 B per wave-frag);
//      blocks [3136,3328): BN stats (sum,sumsq), 16 rows/block.
//      (Proven in R10.) ----
__global__ void k_prep(const float* __restrict__ ent_w,
                       unsigned short* __restrict__ Wb,
                       const int* __restrict__ facts,
                       const float* __restrict__ rel_w,
                       float* __restrict__ stats) {
  if (blockIdx.x < 3136) {
    int nt = blockIdx.x;
    int tid = threadIdx.x;                    // 256
#pragma unroll
    for (int h = 0; h < 2; ++h) {
      int g = h * 256 + tid;                  // granule in [0,512)
      int kc = g >> 6, lane = g & 63;
      int qq = lane >> 4, lnn = lane & 15;
      int row = nt * 16 + lnn, col = kc * 32 + qq * 8;
      short8 v;
      if (row < N_ENT) {
        const float* s = ent_w + row * NDIM + col;
        float4 f0 = *(const float4*)s, f1 = *(const float4*)(s + 4);
        v[0] = (short)f2bf(f0.x); v[1] = (short)f2bf(f0.y);
        v[2] = (short)f2bf(f0.z); v[3] = (short)f2bf(f0.w);
        v[4] = (short)f2bf(f1.x); v[5] = (short)f2bf(f1.y);
        v[6] = (short)f2bf(f1.z); v[7] = (short)f2bf(f1.w);
      } else {
        v = (short8)(0);
      }
      *(short8*)(Wb + nt * 4096 + g * 8) = v;
    }
  } else {
    int sb = blockIdx.x - 3136;               // [0,192)
    int seg = sb >> 6;                        // 0=h, 1=t, 2=r
    int d = threadIdx.x;
    const float* tab = (seg == 2) ? rel_w : ent_w;
    int r0 = (sb & 63) * 16;
    int idxs[16];
#pragma unroll
    for (int i = 0; i < 16; ++i) idxs[i] = facts[(r0 + i) * 3 + seg];
    float s = 0.f, s2 = 0.f;
#pragma unroll
    for (int i = 0; i < 16; ++i) {
      float v = tab[idxs[i] * NDIM + d];
      s += v; s2 += v * v;
    }
    atomicAdd(&stats[(seg * 2 + 0) * NDIM + d], s);
    atomicAdd(&stats[(seg * 2 + 1) * NDIM + d], s2);
  }
}

// ---- K2: BN apply + alpha bilinear -> head/tail vec (bf16) + exact label dots ----
__global__ void k_vectors(const int* __restrict__ facts, const int* __restrict__ arch,
                          const float* __restrict__ ent_w, const float* __restrict__ rel_w,
                          const float* __restrict__ bne_g, const float* __restrict__ bne_b,
                          const float* __restrict__ bnr_g, const float* __restrict__ bnr_b,
                          const float* __restrict__ stats,
                          unsigned short* __restrict__ HVb, float* __restrict__ zlab) {
  __shared__ float sh_he[256], sh_te[256], sh_re[256], sh_alpha[64], sh_red[16];
  int b = blockIdx.x, d = threadIdx.x;
  int h = facts[b * 3 + 0], t = facts[b * 3 + 1], r = facts[b * 3 + 2];
  const float inv = 1.0f / (float)BATCH;
  float mh = stats[0 * 256 + d] * inv, vh = stats[1 * 256 + d] * inv - mh * mh;
  float mt = stats[2 * 256 + d] * inv, vt = stats[3 * 256 + d] * inv - mt * mt;
  float mr = stats[4 * 256 + d] * inv, vr = stats[5 * 256 + d] * inv - mr * mr;
  float sch = rsqrtf(vh + 1e-5f) * bne_g[d], shh = bne_b[d] - mh * sch;
  float sct = rsqrtf(vt + 1e-5f) * bne_g[d], sht = bne_b[d] - mt * sct;
  float scr = rsqrtf(vr + 1e-5f) * bnr_g[d], shr = bnr_b[d] - mr * scr;
  sh_he[d] = ent_w[h * NDIM + d] * sch + shh;
  sh_te[d] = ent_w[t * NDIM + d] * sct + sht;
  sh_re[d] = rel_w[r * NDIM + d] * scr + shr;
  if (d < 64) {
    int a = arch[d];
    sh_alpha[d] = (a == 0) ? 0.f : ((a == 1) ? 1.f : -1.f);
  }
  __syncthreads();
  int k = d >> 6, l = d & 63;
  float hv = 0.f, tv = 0.f;
#pragma unroll
  for (int i = 0; i < 4; ++i) {
    float re_i = sh_re[i * 64 + l];
#pragma unroll
    for (int j = 0; j < 4; ++j) {
      hv += sh_alpha[i * 16 + j * 4 + k] * re_i * sh_te[j * 64 + l];
      tv += sh_alpha[i * 16 + k * 4 + j] * re_i * sh_he[j * 64 + l];
    }
  }
  HVb[b * NDIM + d] = f2bf(hv);
  HVb[(BATCH + b) * NDIM + d] = f2bf(tv);
  float ph = hv * ent_w[h * NDIM + d];
  float pt = tv * ent_w[t * NDIM + d];
  for (int m = 1; m < 64; m <<= 1) { ph += __shfl_xor(ph, m); pt += __shfl_xor(pt, m); }
  int wid = d >> 6;
  if ((d & 63) == 0) { sh_red[wid] = ph; sh_red[8 + wid] = pt; }
  __syncthreads();
  if (d == 0) {
    zlab[b] = sh_red[0] + sh_red[1] + sh_red[2] + sh_red[3];
    zlab[BATCH + b] = sh_red[8] + sh_red[9] + sh_red[10] + sh_red[11];
  }
}

// ---- K3: bf16 MFMA GEMM (2048 x 50176 x 256) + fused finalize.
//   R4's champion body VERBATIM (68.1 us, 128 VGPR, no spill, MfmaUtil 31.5%):
//   A (64x256) staged once to LDS (32 KB swizzled), B direct global->VGPR
//   from fragment-laid Wb (1024 B coalesced per wave-frag), double-buffered,
//   compiler-counted waits, no loop barriers. NSTRIP 16 / grid 512 (R10
//   measured: more blocks = worse). Fused last-block finalize (R7-proven,
//   retire-then-count, no spin). ----
__global__ void __launch_bounds__(256, 2)
k_gemm(const unsigned short* __restrict__ HVb, const unsigned short* __restrict__ Wb,
       float* __restrict__ m1, float* __restrict__ m2,
       const float* __restrict__ zlab, unsigned int* __restrict__ cnt,
       float* __restrict__ out) {
  __shared__ __align__(16) unsigned short As[4 * AM * 64];   // 32 KB, 4 chunks
  __shared__ float sred[4];
  __shared__ int slast;
  const int tid = threadIdx.x;
  const int lane = tid & 63, wn4 = tid >> 6;     // 4 waves = 4 n-quarters
  const int L = blockIdx.x;                      // [0,512)
  const int xcd = L & 7, rr = L >> 3;            // rr in [0,64)
  const int strip = xcd * 2 + (rr >> 5);         // [0,16): strip pinned to one XCD
  const int bm = (rr & 31) * AM;
  const int q = lane >> 4, ln = lane & 15;

  const int ntmine = NTILES / NSTRIP + (strip < (NTILES % NSTRIP) ? 1 : 0); // 12 or 13

  // ---- stage A strip once: 4 chunks x 512 granules ----
#pragma unroll
  for (int c = 0; c < 4; ++c)
#pragma unroll
    for (int i = 0; i < 2; ++i) {
      int G = i * 256 + tid;                     // [0,512)
      int row = G >> 3, slot = G & 7;
      int kg = slot ^ (row & 7);
      async16(HVb + (bm + row) * NDIM + c * 64 + kg * 8,
              (char*)As + c * 8192 + G * 16);
    }

  // A frag read byte-offsets (swizzled); chunk-half parity toggles bit 6
  int aoffq[4];
#pragma unroll
  for (int mi = 0; mi < 4; ++mi) {
    int row = mi * 16 + ln;
    aoffq[mi] = row * 128 + ((q ^ (row & 7)) << 4);
  }

  __syncthreads();                               // A staged (drains the 8 DMA ops)

  // B fragment pointer for this wave's 4 n-subtiles (shorts)
  const unsigned short* bp =
      Wb + (size_t)strip * 65536 + (size_t)wn4 * 16384 + (size_t)lane * 8;

  short8 fa0[4], fa1[4], fb0[4], fb1[4];
  float ps1[4][4] = {}, ps2[4][4] = {};

#define RDA(CN, FA)                                                           \
  {                                                                           \
    const char* Ac = (const char*)As + ((((CN)) & 7) >> 1) * 8192;            \
    const int axor = (((CN)) & 1) << 6;                                       \
    _Pragma("unroll") for (int mi = 0; mi < 4; ++mi)                          \
        FA[mi] = *(const short8*)(Ac + (aoffq[mi] ^ axor));                   \
  }
#define RDB(BP, CN, FB)                                                       \
  _Pragma("unroll") for (int ni = 0; ni < 4; ++ni)                            \
      FB[ni] = *(const short8*)((BP) + (CN) * 512 + ni * 4096);
#define MM(FA, FB)                                                            \
  {                                                                           \
    __builtin_amdgcn_s_setprio(1);                                            \
    _Pragma("unroll") for (int mi = 0; mi < 4; ++mi)                          \
        _Pragma("unroll") for (int ni = 0; ni < 4; ++ni)                      \
            acc[mi][ni] = __builtin_amdgcn_mfma_f32_16x16x32_bf16(            \
                FA[mi], FB[ni], acc[mi][ni], 0, 0, 0);                        \
    __builtin_amdgcn_s_setprio(0);                                            \
  }

  RDA(0, fa0); RDB(bp, 0, fb0);                  // prologue frags
  for (int ti = 0; ti < ntmine; ++ti) {
    const unsigned short* bpn =
        (ti + 1 < ntmine) ? bp + (size_t)NSTRIP * 65536 : bp;   // clamp = dummy
    f32x4 acc[4][4] = {};
    RDA(1, fa1); RDB(bp, 1, fb1);  MM(fa0, fb0);
    RDA(2, fa0); RDB(bp, 2, fb0);  MM(fa1, fb1);
    RDA(3, fa1); RDB(bp, 3, fb1);  MM(fa0, fb0);
    RDA(4, fa0); RDB(bp, 4, fb0);  MM(fa1, fb1);
    RDA(5, fa1); RDB(bp, 5, fb1);  MM(fa0, fb0);
    RDA(6, fa0); RDB(bp, 6, fb0);  MM(fa1, fb1);
    RDA(7, fa1); RDB(bp, 7, fb1);  MM(fa0, fb0);
    RDA(0, fa0); RDB(bpn, 0, fb0); MM(fa1, fb1); // preload next tile's phase 0
    bp = bpn;
    // consume acc into register power sums (pad cols contribute e^-30 ~ 0);
    // overlaps the next tile's phase-0 load latency
#pragma unroll
    for (int mi = 0; mi < 4; ++mi)
#pragma unroll
      for (int reg = 0; reg < 4; ++reg) {
        float s1 = 0.f, s2 = 0.f;
#pragma unroll
        for (int ni = 0; ni < 4; ++ni) {
          float e1 = __expf(acc[mi][ni][reg] - SHIFT);
          s1 += e1; s2 += e1 * e1;
        }
        ps1[mi][reg] += s1;
        ps2[mi][reg] += s2;
      }
  }
#undef MM
#undef RDB
#undef RDA

  // one reduce + atomic round per block
#pragma unroll
  for (int mi = 0; mi < 4; ++mi)
#pragma unroll
    for (int reg = 0; reg < 4; ++reg) {
      float s1 = ps1[mi][reg], s2 = ps2[mi][reg];
      for (int m = 1; m < 16; m <<= 1) { s1 += __shfl_xor(s1, m); s2 += __shfl_xor(s2, m); }
      if (ln == 0) {
        int grow = bm + mi * 16 + q * 4 + reg;
        atomicAdd(&m1[grow], s1);
        atomicAdd(&m2[grow], s2);
      }
    }

  // ---- fused finalize: last of 512 blocks assembles the loss (R7-proven) ----
  __threadfence();
  if (tid == 0) slast = (atomicAdd(cnt, 1u) + 1u == 512u) ? 1 : 0;
  __syncthreads();
  if (slast) {
    __threadfence();
    float local = 0.f;
    for (int r = tid; r < MROWS; r += 256) {
      float M1 = __hip_atomic_load(&m1[r], __ATOMIC_RELAXED, __HIP_MEMORY_SCOPE_AGENT);
      float M2 = __hip_atomic_load(&m2[r], __ATOMIC_RELAXED, __HIP_MEMORY_SCOPE_AGENT);
      float lse = SHIFT + logf(M1);
      float zl = zlab[r];
      float lp = fmaxf(zl - lse, -100.f);                 // log p_label
      float pl = __expf(zl - lse);
      float l1m = fmaxf(log1pf(-pl), -100.f);             // log(1-p_label)
      float iM1 = 1.f / M1;
      float r2 = M2 * iM1 * iM1;
      // sum_e log1p(-p_e) = -(1 + sum p^2/2 + O(p^3)); sum p == 1 exactly
      local += lp - l1m - (1.f + 0.5f * r2);
    }
    for (int m = 1; m < 64; m <<= 1) local += __shfl_xor(local, m);
    if ((tid & 63) == 0) sred[tid >> 6] = local;
    __syncthreads();
    if (tid == 0) {
      float ssum = sred[0] + sred[1] + sred[2] + sred[3];
      out[0] = -ssum / ((float)BATCH * (float)N_ENT);
    }
  }
}

extern "C" void kernel_launch(void* const* d_in, const int* in_sizes, int n_in,
                              void* d_out, int out_size, void* d_ws, size_t ws_size,
                              hipStream_t stream) {
  const int* facts = (const int*)d_in[0];
  const int* arch = (const int*)d_in[1];
  const float* ent_w = (const float*)d_in[2];
  const float* rel_w = (const float*)d_in[3];
  const float* bne_g = (const float*)d_in[4];
  const float* bne_b = (const float*)d_in[5];
  const float* bnr_g = (const float*)d_in[6];
  const float* bnr_b = (const float*)d_in[7];
  char* ws = (char*)d_ws;
  // layout: [stats 6144][m1 8192][m2 8192][cnt 16 @22528][zlab @24576 8192]
  //         [HVb @32768 1MB][Wb 25.7MB]
  float* stats = (float*)ws;
  float* m1 = (float*)(ws + 6144);
  float* m2 = (float*)(ws + 14336);
  unsigned int* cnt = (unsigned int*)(ws + 22528);
  float* zlab = (float*)(ws + 24576);
  unsigned short* HVb = (unsigned short*)(ws + 32768);
  unsigned short* Wb = (unsigned short*)(ws + 32768 + 1048576);

  hipMemsetAsync(ws, 0, 22544, stream);  // stats + m1 + m2 + cnt
  k_prep<<<dim3(3328), dim3(256), 0, stream>>>(ent_w, Wb, facts, rel_w, stats);
  k_vectors<<<dim3(BATCH), dim3(256), 0, stream>>>(facts, arch, ent_w, rel_w,
                                                   bne_g, bne_b, bnr_g, bnr_b,
                                                   stats, HVb, zlab);
  k_gemm<<<dim3(512), dim3(256), 0, stream>>>(HVb, Wb, m1, m2, zlab, cnt,
                                              (float*)d_out);
}

// Round 12
// 171.851 us; speedup vs baseline: 1.1731x; 1.1731x over previous
//
#include <hip/hip_runtime.h>

#define N_ENT   50000
#define N_ENT_P 50176
#define NDIM    256
#define BATCH   1024
#define MROWS   2048
#define AM      64
#define NTILES  196
#define NSTRIP  16
#define SHIFT   30.0f

typedef __attribute__((ext_vector_type(8))) short short8;
typedef __attribute__((ext_vector_type(4))) float f32x4;

__device__ __forceinline__ unsigned short f2bf(float f) {
  unsigned int u = __float_as_uint(f);
  u += 0x7fffu + ((u >> 16) & 1u);          // RNE
  return (unsigned short)(u >> 16);
}

__device__ __forceinline__ void async16(const void* g, void* lds) {
  __builtin_amdgcn_global_load_lds(
      (const __attribute__((address_space(1))) unsigned int*)g,
      (__attribute__((address_space(3))) unsigned int*)lds,
      16, 0, 0);
}

// ---- K0 (fused): blocks [0,3136): ent_w f32 -> bf16 MFMA-FRAGMENT layout
//      (granule (nt,kc,lane)=B[nt*16+ln][kc*32+q*8..+7], 1024 B per wave-frag,
//      fully coalesced writes); blocks [3136,3328): BN stats (sum,sumsq).
//      (Proven R10/R11; neutral vs separate dispatches.) ----
__global__ void k_prep(const float* __restrict__ ent_w,
                       unsigned short* __restrict__ Wb,
                       const int* __restrict__ facts,
                       const float* __restrict__ rel_w,
                       float* __restrict__ stats) {
  if (blockIdx.x < 3136) {
    int nt = blockIdx.x;
    int tid = threadIdx.x;                    // 256
#pragma unroll
    for (int h = 0; h < 2; ++h) {
      int g = h * 256 + tid;                  // granule in [0,512)
      int kc = g >> 6, lane = g & 63;
      int qq = lane >> 4, lnn = lane & 15;
      int row = nt * 16 + lnn, col = kc * 32 + qq * 8;
      short8 v;
      if (row < N_ENT) {
        const float* s = ent_w + row * NDIM + col;
        float4 f0 = *(const float4*)s, f1 = *(const float4*)(s + 4);
        v[0] = (short)f2bf(f0.x); v[1] = (short)f2bf(f0.y);
        v[2] = (short)f2bf(f0.z); v[3] = (short)f2bf(f0.w);
        v[4] = (short)f2bf(f1.x); v[5] = (short)f2bf(f1.y);
        v[6] = (short)f2bf(f1.z); v[7] = (short)f2bf(f1.w);
      } else {
        v = (short8)(0);
      }
      *(short8*)(Wb + nt * 4096 + g * 8) = v;
    }
  } else {
    int sb = blockIdx.x - 3136;               // [0,192)
    int seg = sb >> 6;                        // 0=h, 1=t, 2=r
    int d = threadIdx.x;
    const float* tab = (seg == 2) ? rel_w : ent_w;
    int r0 = (sb & 63) * 16;
    int idxs[16];
#pragma unroll
    for (int i = 0; i < 16; ++i) idxs[i] = facts[(r0 + i) * 3 + seg];
    float s = 0.f, s2 = 0.f;
#pragma unroll
    for (int i = 0; i < 16; ++i) {
      float v = tab[idxs[i] * NDIM + d];
      s += v; s2 += v * v;
    }
    atomicAdd(&stats[(seg * 2 + 0) * NDIM + d], s);
    atomicAdd(&stats[(seg * 2 + 1) * NDIM + d], s2);
  }
}

// ---- K2: BN apply + alpha bilinear -> head/tail vec (bf16) + exact label dots ----
__global__ void k_vectors(const int* __restrict__ facts, const int* __restrict__ arch,
                          const float* __restrict__ ent_w, const float* __restrict__ rel_w,
                          const float* __restrict__ bne_g, const float* __restrict__ bne_b,
                          const float* __restrict__ bnr_g, const float* __restrict__ bnr_b,
                          const float* __restrict__ stats,
                          unsigned short* __restrict__ HVb, float* __restrict__ zlab) {
  __shared__ float sh_he[256], sh_te[256], sh_re[256], sh_alpha[64], sh_red[16];
  int b = blockIdx.x, d = threadIdx.x;
  int h = facts[b * 3 + 0], t = facts[b * 3 + 1], r = facts[b * 3 + 2];
  const float inv = 1.0f / (float)BATCH;
  float mh = stats[0 * 256 + d] * inv, vh = stats[1 * 256 + d] * inv - mh * mh;
  float mt = stats[2 * 256 + d] * inv, vt = stats[3 * 256 + d] * inv - mt * mt;
  float mr = stats[4 * 256 + d] * inv, vr = stats[5 * 256 + d] * inv - mr * mr;
  float sch = rsqrtf(vh + 1e-5f) * bne_g[d], shh = bne_b[d] - mh * sch;
  float sct = rsqrtf(vt + 1e-5f) * bne_g[d], sht = bne_b[d] - mt * sct;
  float scr = rsqrtf(vr + 1e-5f) * bnr_g[d], shr = bnr_b[d] - mr * scr;
  sh_he[d] = ent_w[h * NDIM + d] * sch + shh;
  sh_te[d] = ent_w[t * NDIM + d] * sct + sht;
  sh_re[d] = rel_w[r * NDIM + d] * scr + shr;
  if (d < 64) {
    int a = arch[d];
    sh_alpha[d] = (a == 0) ? 0.f : ((a == 1) ? 1.f : -1.f);
  }
  __syncthreads();
  int k = d >> 6, l = d & 63;
  float hv = 0.f, tv = 0.f;
#pragma unroll
  for (int i = 0; i < 4; ++i) {
    float re_i = sh_re[i * 64 + l];
#pragma unroll
    for (int j = 0; j < 4; ++j) {
      hv += sh_alpha[i * 16 + j * 4 + k] * re_i * sh_te[j * 64 + l];
      tv += sh_alpha[i * 16 + k * 4 + j] * re_i * sh_he[j * 64 + l];
    }
  }
  HVb[b * NDIM + d] = f2bf(hv);
  HVb[(BATCH + b) * NDIM + d] = f2bf(tv);
  float ph = hv * ent_w[h * NDIM + d];
  float pt = tv * ent_w[t * NDIM + d];
  for (int m = 1; m < 64; m <<= 1) { ph += __shfl_xor(ph, m); pt += __shfl_xor(pt, m); }
  int wid = d >> 6;
  if ((d & 63) == 0) { sh_red[wid] = ph; sh_red[8 + wid] = pt; }
  __syncthreads();
  if (d == 0) {
    zlab[b] = sh_red[0] + sh_red[1] + sh_red[2] + sh_red[3];
    zlab[BATCH + b] = sh_red[8] + sh_red[9] + sh_red[10] + sh_red[11];
  }
}

// ---- K3: bf16 MFMA GEMM (2048 x 50176 x 256) — R4 champion VERBATIM
//   (68.1 us, 128 VGPR, no spill, MfmaUtil 31.5%, 0 bank conflicts).
//   A (64x256) staged once to LDS (32 KB swizzled); B direct global->VGPR
//   from fragment-laid Wb (1024 B coalesced per wave-frag), double-buffered,
//   compiler-counted waits, no loop barriers. NSTRIP 16 / grid 512.
//   NO fused finalize: R11 measured the in-kernel finalize at +34 us. ----
__global__ void __launch_bounds__(256, 2)
k_gemm(const unsigned short* __restrict__ HVb, const unsigned short* __restrict__ Wb,
       float* __restrict__ m1, float* __restrict__ m2) {
  __shared__ __align__(16) unsigned short As[4 * AM * 64];   // 32 KB, 4 chunks
  const int tid = threadIdx.x;
  const int lane = tid & 63, wn4 = tid >> 6;     // 4 waves = 4 n-quarters
  const int L = blockIdx.x;                      // [0,512)
  const int xcd = L & 7, rr = L >> 3;            // rr in [0,64)
  const int strip = xcd * 2 + (rr >> 5);         // [0,16): strip pinned to one XCD
  const int bm = (rr & 31) * AM;
  const int q = lane >> 4, ln = lane & 15;

  const int ntmine = NTILES / NSTRIP + (strip < (NTILES % NSTRIP) ? 1 : 0); // 12 or 13

  // ---- stage A strip once: 4 chunks x 512 granules ----
#pragma unroll
  for (int c = 0; c < 4; ++c)
#pragma unroll
    for (int i = 0; i < 2; ++i) {
      int G = i * 256 + tid;                     // [0,512)
      int row = G >> 3, slot = G & 7;
      int kg = slot ^ (row & 7);
      async16(HVb + (bm + row) * NDIM + c * 64 + kg * 8,
              (char*)As + c * 8192 + G * 16);
    }

  // A frag read byte-offsets (swizzled); chunk-half parity toggles bit 6
  int aoffq[4];
#pragma unroll
  for (int mi = 0; mi < 4; ++mi) {
    int row = mi * 16 + ln;
    aoffq[mi] = row * 128 + ((q ^ (row & 7)) << 4);
  }

  __syncthreads();                               // A staged (drains the 8 DMA ops)

  // B fragment pointer for this wave's 4 n-subtiles (shorts)
  const unsigned short* bp =
      Wb + (size_t)strip * 65536 + (size_t)wn4 * 16384 + (size_t)lane * 8;

  short8 fa0[4], fa1[4], fb0[4], fb1[4];
  float ps1[4][4] = {}, ps2[4][4] = {};

#define RDA(CN, FA)                                                           \
  {                                                                           \
    const char* Ac = (const char*)As + ((((CN)) & 7) >> 1) * 8192;            \
    const int axor = (((CN)) & 1) << 6;                                       \
    _Pragma("unroll") for (int mi = 0; mi < 4; ++mi)                          \
        FA[mi] = *(const short8*)(Ac + (aoffq[mi] ^ axor));                   \
  }
#define RDB(BP, CN, FB)                                                       \
  _Pragma("unroll") for (int ni = 0; ni < 4; ++ni)                            \
      FB[ni] = *(const short8*)((BP) + (CN) * 512 + ni * 4096);
#define MM(FA, FB)                                                            \
  {                                                                           \
    __builtin_amdgcn_s_setprio(1);                                            \
    _Pragma("unroll") for (int mi = 0; mi < 4; ++mi)                          \
        _Pragma("unroll") for (int ni = 0; ni < 4; ++ni)                      \
            acc[mi][ni] = __builtin_amdgcn_mfma_f32_16x16x32_bf16(            \
                FA[mi], FB[ni], acc[mi][ni], 0, 0, 0);                        \
    __builtin_amdgcn_s_setprio(0);                                            \
  }

  RDA(0, fa0); RDB(bp, 0, fb0);                  // prologue frags
  for (int ti = 0; ti < ntmine; ++ti) {
    const unsigned short* bpn =
        (ti + 1 < ntmine) ? bp + (size_t)NSTRIP * 65536 : bp;   // clamp = dummy
    f32x4 acc[4][4] = {};
    RDA(1, fa1); RDB(bp, 1, fb1);  MM(fa0, fb0);
    RDA(2, fa0); RDB(bp, 2, fb0);  MM(fa1, fb1);
    RDA(3, fa1); RDB(bp, 3, fb1);  MM(fa0, fb0);
    RDA(4, fa0); RDB(bp, 4, fb0);  MM(fa1, fb1);
    RDA(5, fa1); RDB(bp, 5, fb1);  MM(fa0, fb0);
    RDA(6, fa0); RDB(bp, 6, fb0);  MM(fa1, fb1);
    RDA(7, fa1); RDB(bp, 7, fb1);  MM(fa0, fb0);
    RDA(0, fa0); RDB(bpn, 0, fb0); MM(fa1, fb1); // preload next tile's phase 0
    bp = bpn;
    // consume acc into register power sums (pad cols contribute e^-30 ~ 0);
    // overlaps the next tile's phase-0 load latency
#pragma unroll
    for (int mi = 0; mi < 4; ++mi)
#pragma unroll
      for (int reg = 0; reg < 4; ++reg) {
        float s1 = 0.f, s2 = 0.f;
#pragma unroll
        for (int ni = 0; ni < 4; ++ni) {
          float e1 = __expf(acc[mi][ni][reg] - SHIFT);
          s1 += e1; s2 += e1 * e1;
        }
        ps1[mi][reg] += s1;
        ps2[mi][reg] += s2;
      }
  }
#undef MM
#undef RDB
#undef RDA

  // one reduce + atomic round per block
#pragma unroll
  for (int mi = 0; mi < 4; ++mi)
#pragma unroll
    for (int reg = 0; reg < 4; ++reg) {
      float s1 = ps1[mi][reg], s2 = ps2[mi][reg];
      for (int m = 1; m < 16; m <<= 1) { s1 += __shfl_xor(s1, m); s2 += __shfl_xor(s2, m); }
      if (ln == 0) {
        int grow = bm + mi * 16 + q * 4 + reg;
        atomicAdd(&m1[grow], s1);
        atomicAdd(&m2[grow], s2);
      }
    }
}

// ---- K4: per-row loss assembly + scalar reduce (separate dispatch ~5 us;
//      fused variant measured +34 us inside k_gemm — R11) ----
__global__ void k_finalize(const float* __restrict__ m1, const float* __restrict__ m2,
                           const float* __restrict__ zlab, float* __restrict__ out) {
  __shared__ float red[16];
  int tid = threadIdx.x;  // 1024 threads
  float local = 0.f;
  for (int r = tid; r < MROWS; r += 1024) {
    float M1 = m1[r];
    float lse = SHIFT + logf(M1);
    float zl = zlab[r];
    float lp = fmaxf(zl - lse, -100.f);                 // log p_label
    float pl = __expf(zl - lse);
    float l1m = fmaxf(log1pf(-pl), -100.f);             // log(1-p_label)
    float iM1 = 1.f / M1;
    float r2 = m2[r] * iM1 * iM1;
    // sum_e log1p(-p_e) = -(1 + sum p^2/2 + O(p^3)); sum p == 1 exactly
    float series = -(1.f + 0.5f * r2);
    local += lp - l1m + series;
  }
  for (int m = 1; m < 64; m <<= 1) local += __shfl_xor(local, m);
  if ((tid & 63) == 0) red[tid >> 6] = local;
  __syncthreads();
  if (tid == 0) {
    float s = 0.f;
    for (int i = 0; i < 16; ++i) s += red[i];
    out[0] = -s / ((float)BATCH * (float)N_ENT);
  }
}

extern "C" void kernel_launch(void* const* d_in, const int* in_sizes, int n_in,
                              void* d_out, int out_size, void* d_ws, size_t ws_size,
                              hipStream_t stream) {
  const int* facts = (const int*)d_in[0];
  const int* arch = (const int*)d_in[1];
  const float* ent_w = (const float*)d_in[2];
  const float* rel_w = (const float*)d_in[3];
  const float* bne_g = (const float*)d_in[4];
  const float* bne_b = (const float*)d_in[5];
  const float* bnr_g = (const float*)d_in[6];
  const float* bnr_b = (const float*)d_in[7];
  char* ws = (char*)d_ws;
  // layout: [stats 6144][m1 8192][m2 8192][zlab 8192][HVb 1MB][Wb 25.7MB]
  float* stats = (float*)ws;
  float* m1 = (float*)(ws + 6144);
  float* m2 = (float*)(ws + 14336);
  float* zlab = (float*)(ws + 22528);
  unsigned short* HVb = (unsigned short*)(ws + 30720);
  unsigned short* Wb = (unsigned short*)(ws + 30720 + 1048576);

  hipMemsetAsync(ws, 0, 22528, stream);  // stats + m1 + m2
  k_prep<<<dim3(3328), dim3(256), 0, stream>>>(ent_w, Wb, facts, rel_w, stats);
  k_vectors<<<dim3(BATCH), dim3(256), 0, stream>>>(facts, arch, ent_w, rel_w,
                                                   bne_g, bne_b, bnr_g, bnr_b,
                                                   stats, HVb, zlab);
  k_gemm<<<dim3(512), dim3(256), 0, stream>>>(HVb, Wb, m1, m2);
  k_finalize<<<dim3(1), dim3(1024), 0, stream>>>(m1, m2, zlab, (float*)d_out);
}